// Round 1
// baseline (87.615 us; speedup 1.0000x reference)
//
#include <hip/hip_runtime.h>

#define BATCH 512
#define T 256
#define C 384
#define H 64

typedef __bf16 bf16x8 __attribute__((ext_vector_type(8)));
typedef float f32x4 __attribute__((ext_vector_type(4)));

// LDS byte map.
// Phase 1: Xs @0 (32KB): [256][64] bf16, row stride 128B, swizzle ^((row&7)<<4)
//          Ws @32768 (24KB): 3 x [64 h][64 k] bf16 (W^T), row stride 128B, same swizzle
// Phase 2 (overlaps phase-1 regions, separated by barriers):
//          Qs @0, Ks @32768 ([256][64] bf16 row-major, swizzled)
//          VT @65536 ([64 h][256 t] bf16, row stride 512B, swizzle ^((h&7)<<4))
//          Ps @98304 (8 waves x 1KB: [16 q][32 k] bf16, row stride 64B, swizzle ^((q&3)<<4))
#define XS_OFF 0
#define WS_OFF 32768
#define QS_OFF 0
#define KS_OFF 32768
#define VT_OFF 65536
#define PS_OFF 98304
#define LDS_BYTES 106496

__global__ __launch_bounds__(512, 2) void head_fused(
    const float* __restrict__ x, const float* __restrict__ Wk,
    const float* __restrict__ Wq, const float* __restrict__ Wv,
    float* __restrict__ out)
{
    __shared__ __align__(16) unsigned char lds[LDS_BYTES];
    const int tid  = threadIdx.x;
    const int w    = tid >> 6;        // wave 0..7
    const int lane = tid & 63;
    const int l15  = lane & 15;
    const int g    = lane >> 4;       // lane group 0..3
    const int b    = blockIdx.x;
    const float* xb = x + (size_t)b * T * C;
    const float* wm[3] = {Wq, Wk, Wv};   // m=0:Q 1:K 2:V

    // ---------------- Phase 1: projections Q,K,V = X * W ----------------
    f32x4 acc[3][2][4];
#pragma unroll
    for (int m = 0; m < 3; ++m)
#pragma unroll
        for (int mt = 0; mt < 2; ++mt)
#pragma unroll
            for (int n = 0; n < 4; ++n)
                acc[m][mt][n] = (f32x4){0.f, 0.f, 0.f, 0.f};

    for (int kt = 0; kt < 6; ++kt) {   // 6 outer K-steps of 64 over C=384
        // stage X[:, kt*64 .. +64) -> Xs (bf16, swizzled)
        {
            const int c0 = (tid & 7) << 3;
#pragma unroll
            for (int it = 0; it < 4; ++it) {
                const int t = (tid >> 3) + (it << 6);
                const float* src = xb + t * C + kt * 64 + c0;
                const float4 f0 = *reinterpret_cast<const float4*>(src);
                const float4 f1 = *reinterpret_cast<const float4*>(src + 4);
                bf16x8 v;
                v[0] = (__bf16)f0.x; v[1] = (__bf16)f0.y; v[2] = (__bf16)f0.z; v[3] = (__bf16)f0.w;
                v[4] = (__bf16)f1.x; v[5] = (__bf16)f1.y; v[6] = (__bf16)f1.z; v[7] = (__bf16)f1.w;
                const int off = XS_OFF + t * 128 + ((c0 * 2) ^ ((t & 7) << 4));
                *reinterpret_cast<bf16x8*>(lds + off) = v;
            }
        }
        // stage W^T tiles: Ws[m][h][k] = W[kt*64+k][h]
        {
            const int k  = tid >> 3;
            const int h0 = (tid & 7) << 3;
#pragma unroll
            for (int m = 0; m < 3; ++m) {
                const float* src = wm[m] + (kt * 64 + k) * H + h0;
                const float4 f0 = *reinterpret_cast<const float4*>(src);
                const float4 f1 = *reinterpret_cast<const float4*>(src + 4);
                const float vals[8] = {f0.x, f0.y, f0.z, f0.w, f1.x, f1.y, f1.z, f1.w};
#pragma unroll
                for (int j = 0; j < 8; ++j) {
                    const int hr  = h0 + j;
                    const int off = WS_OFF + m * 8192 + hr * 128 + ((2 * k) ^ ((hr & 7) << 4));
                    *reinterpret_cast<__bf16*>(lds + off) = (__bf16)vals[j];
                }
            }
        }
        __syncthreads();

        // A fragments (shared across the 3 matrices)
        bf16x8 af[2][2];
#pragma unroll
        for (int mt = 0; mt < 2; ++mt) {
            const int row = (2 * w + mt) * 16 + l15;
#pragma unroll
            for (int ks = 0; ks < 2; ++ks) {
                const int off = XS_OFF + row * 128 + (((ks * 64) + (g * 16)) ^ ((row & 7) << 4));
                af[mt][ks] = *reinterpret_cast<const bf16x8*>(lds + off);
            }
        }
#pragma unroll
        for (int m = 0; m < 3; ++m) {
#pragma unroll
            for (int n = 0; n < 4; ++n) {
                const int brow = n * 16 + l15;
#pragma unroll
                for (int ks = 0; ks < 2; ++ks) {
                    const int off = WS_OFF + m * 8192 + brow * 128 + (((ks * 64) + (g * 16)) ^ ((brow & 7) << 4));
                    const bf16x8 bfr = *reinterpret_cast<const bf16x8*>(lds + off);
#pragma unroll
                    for (int mt = 0; mt < 2; ++mt)
                        acc[m][mt][n] = __builtin_amdgcn_mfma_f32_16x16x32_bf16(af[mt][ks], bfr, acc[m][mt][n], 0, 0, 0);
                }
            }
        }
        __syncthreads();
    }

    // epilogue: Q,K row-major; V transposed. D layout: col=l15, row=g*4+r.
#pragma unroll
    for (int m = 0; m < 3; ++m) {
#pragma unroll
        for (int mt = 0; mt < 2; ++mt) {
#pragma unroll
            for (int n = 0; n < 4; ++n) {
#pragma unroll
                for (int r = 0; r < 4; ++r) {
                    const __bf16 bv  = (__bf16)acc[m][mt][n][r];
                    const int trow = (2 * w + mt) * 16 + g * 4 + r;  // t index
                    const int hcol = n * 16 + l15;                   // h index
                    int off;
                    if (m == 2)
                        off = VT_OFF + hcol * 512 + ((2 * trow) ^ ((hcol & 7) << 4));
                    else
                        off = (m == 0 ? QS_OFF : KS_OFF) + trow * 128 + ((2 * hcol) ^ ((trow & 7) << 4));
                    *reinterpret_cast<__bf16*>(lds + off) = bv;
                }
            }
        }
    }
    __syncthreads();

    // ---------------- Phase 2: causal attention ----------------
    const float scale = 0.051031036307982884f;  // 384^-0.5
#pragma unroll 1
    for (int hf = 0; hf < 2; ++hf) {
        const int mt = 2 * w + hf;     // q-tile 0..15
        const int q0 = mt * 16;

        bf16x8 qf[2];
        {
            const int row = q0 + l15;
#pragma unroll
            for (int ks = 0; ks < 2; ++ks) {
                const int off = QS_OFF + row * 128 + (((ks * 64) + (g * 16)) ^ ((row & 7) << 4));
                qf[ks] = *reinterpret_cast<const bf16x8*>(lds + off);
            }
        }

        f32x4 s[16];
#pragma unroll
        for (int n = 0; n < 16; ++n) s[n] = (f32x4){0.f, 0.f, 0.f, 0.f};
#pragma unroll
        for (int n = 0; n < 16; ++n) {
            const int brow = n * 16 + l15;
#pragma unroll
            for (int ks = 0; ks < 2; ++ks) {
                const int off = KS_OFF + brow * 128 + (((ks * 64) + (g * 16)) ^ ((brow & 7) << 4));
                const bf16x8 bfr = *reinterpret_cast<const bf16x8*>(lds + off);
                s[n] = __builtin_amdgcn_mfma_f32_16x16x32_bf16(qf[ks], bfr, s[n], 0, 0, 0);
            }
        }

        // scale + causal mask; row q = q0+g*4+r lives across 16 lanes (col k = n*16+l15)
        float mrow[4] = {-1e30f, -1e30f, -1e30f, -1e30f};
#pragma unroll
        for (int n = 0; n < 16; ++n) {
#pragma unroll
            for (int r = 0; r < 4; ++r) {
                float v = s[n][r] * scale;
                if (n * 16 + l15 > q0 + g * 4 + r) v = -1e30f;
                s[n][r] = v;
                mrow[r] = fmaxf(mrow[r], v);
            }
        }
#pragma unroll
        for (int d = 1; d < 16; d <<= 1)
#pragma unroll
            for (int r = 0; r < 4; ++r)
                mrow[r] = fmaxf(mrow[r], __shfl_xor(mrow[r], d));

        float ssum[4] = {0.f, 0.f, 0.f, 0.f};
#pragma unroll
        for (int n = 0; n < 16; ++n) {
#pragma unroll
            for (int r = 0; r < 4; ++r) {
                const float p = __expf(s[n][r] - mrow[r]);
                s[n][r] = p;
                ssum[r] += p;
            }
        }
#pragma unroll
        for (int d = 1; d < 16; d <<= 1)
#pragma unroll
            for (int r = 0; r < 4; ++r)
                ssum[r] += __shfl_xor(ssum[r], d);

        // PV: stage unnormalized P chunks (16q x 32k) through per-wave LDS, MFMA with V^T
        f32x4 o[4];
#pragma unroll
        for (int nh = 0; nh < 4; ++nh) o[nh] = (f32x4){0.f, 0.f, 0.f, 0.f};
#pragma unroll
        for (int cc = 0; cc < 8; ++cc) {
#pragma unroll
            for (int hn = 0; hn < 2; ++hn) {
                const int n = 2 * cc + hn;
#pragma unroll
                for (int r = 0; r < 4; ++r) {
                    const int prow = g * 4 + r;
                    const int pcol = hn * 16 + l15;
                    const int off = PS_OFF + w * 1024 + prow * 64 + ((2 * pcol) ^ ((prow & 3) << 4));
                    *reinterpret_cast<__bf16*>(lds + off) = (__bf16)s[n][r];
                }
            }
            bf16x8 pf;
            {
                const int off = PS_OFF + w * 1024 + l15 * 64 + ((g * 16) ^ ((l15 & 3) << 4));
                pf = *reinterpret_cast<const bf16x8*>(lds + off);
            }
#pragma unroll
            for (int nh = 0; nh < 4; ++nh) {
                const int hrow = nh * 16 + l15;
                const int off = VT_OFF + hrow * 512 + (((cc * 64) + (g * 16)) ^ ((hrow & 7) << 4));
                const bf16x8 vf = *reinterpret_cast<const bf16x8*>(lds + off);
                o[nh] = __builtin_amdgcn_mfma_f32_16x16x32_bf16(pf, vf, o[nh], 0, 0, 0);
            }
        }

        float inv[4];
#pragma unroll
        for (int r = 0; r < 4; ++r) inv[r] = 1.0f / ssum[r];
        float* ob = out + ((size_t)b * T + q0) * H;
#pragma unroll
        for (int nh = 0; nh < 4; ++nh)
#pragma unroll
            for (int r = 0; r < 4; ++r)
                ob[(g * 4 + r) * H + nh * 16 + l15] = o[nh][r] * inv[r];
    }
}

extern "C" void kernel_launch(void* const* d_in, const int* in_sizes, int n_in,
                              void* d_out, int out_size, void* d_ws, size_t ws_size,
                              hipStream_t stream) {
    (void)in_sizes; (void)n_in; (void)d_ws; (void)ws_size; (void)out_size;
    const float* x  = (const float*)d_in[0];
    const float* Wk = (const float*)d_in[1];
    const float* Wq = (const float*)d_in[2];
    const float* Wv = (const float*)d_in[3];
    float* out = (float*)d_out;
    head_fused<<<dim3(BATCH), dim3(512), 0, stream>>>(x, Wk, Wq, Wv, out);
}